// Round 4
// baseline (628.449 us; speedup 1.0000x reference)
//
#include <hip/hip_runtime.h>
#include <cstdint>

#define NCOLS   696    // 16 + 120 + 560 subsets of size <= 3, bitmask order
#define RG      64     // rows per wave: lane = row
#define BLOCK   256    // 4 waves: 2 row-groups x 2 column-halves
#define SPLIT   344    // column split; 344 % 8 == 0 and position 344 = pair(9,12)
#define VSTRIDE 17     // float2 row stride in LDS (odd -> max 4-way bank aliasing)

typedef float v4f __attribute__((ext_vector_type(4)));

// Per-position descriptor, wave-uniform: x[3:0], y[7:4], tri[8].
//   single h      : (x=h, y=h, 0)  -> selpair(V[h],V[h]) == V[h] (tie -> left)
//   pair  (j,h)   : (x=j, y=h, 0)  -> selpair(V[h],V[j]); becomes L-cache
//   triple(i,j,h) : (x=i, y=j, 1)  -> R = selpair(V[j],V[i]); out = selpair(Lc, R)
// Emission order (h; j<h: pair then i<j triples) == bitmask-sorted order, and
// every triple is immediately preceded (within its j-run) by its L pair.
struct alignas(16) Tab { uint32_t d[NCOLS]; };
constexpr Tab make_tab() {
    Tab t{};
    int p = 0;
    for (int h = 0; h < 16; ++h) {
        t.d[p++] = (uint32_t)(h | (h << 4));
        for (int j = 0; j < h; ++j) {
            t.d[p++] = (uint32_t)(j | (h << 4));
            for (int i = 0; i < j; ++i)
                t.d[p++] = (uint32_t)(i | (j << 4) | 256u);
        }
    }
    return t;
}
__constant__ Tab g_tab = make_tab();

// Tie-exact select. cur comparison uses the sum proxy: RN(0.5l+0.5u) =
// 0.5*RN(l+u) exactly (power-of-two scaling), so ==/> are preserved
// bit-for-bit vs the NumPy fp32 reference. Beta path kept in RN form.
__device__ __forceinline__ float2 selpair(float2 L, float2 R) {
    float curL = __fadd_rn(L.x, L.y);
    float curR = __fadd_rn(R.x, R.y);
    float bL = __fadd_rn(__fmul_rn(0.2f, L.x), __fmul_rn(0.8f, L.y));
    float bR = __fadd_rn(__fmul_rn(0.2f, R.x), __fmul_rn(0.8f, R.y));
    bool choose_right = (curL == curR) ? (bL > bR) : (curL > curR);
    return choose_right ? R : L;
}

// lane = row: all column descriptors are wave-uniform (s_load), so there are
// ZERO data-dependent LDS gathers (the R0-R3 kernels' suspected 60-80us).
// LDS holds only the 16 input intervals per row at a conflict-controlled
// stride. Stores are cached (NOT nontemporal: 16B-per-lane chunks rely on L2
// write-back merging 4 consecutive chunks into full 128B lines).
__global__ __launch_bounds__(BLOCK, 2) void minint_kernel(
    const float* __restrict__ xl, const float* __restrict__ xu,
    float* __restrict__ out, int batch)
{
    __shared__ float2 vv[4][RG * VSTRIDE];   // 34.8 KB total, wave-private slabs
    const int t    = threadIdx.x;
    const int w    = t >> 6;
    const int lane = t & 63;
    const int rg   = blockIdx.x * 2 + (w >> 1);   // row-group
    const int row  = rg * RG + lane;
    const int half = w & 1;                       // column half

    // Stage this lane's row: 16 xl + 16 xu -> interleaved float2 in LDS.
    const float4* l4 = (const float4*)(xl + (size_t)row * 16);
    const float4* u4 = (const float4*)(xu + (size_t)row * 16);
    float2* vrow = &vv[w][lane * VSTRIDE];
#pragma unroll
    for (int q = 0; q < 4; ++q) {
        float4 a = l4[q], b = u4[q];
        vrow[4 * q + 0] = make_float2(a.x, b.x);
        vrow[4 * q + 1] = make_float2(a.y, b.y);
        vrow[4 * q + 2] = make_float2(a.z, b.z);
        vrow[4 * q + 3] = make_float2(a.w, b.w);
    }
    // RAW on same __shared__ array: compiler inserts lgkmcnt; wave-private,
    // so no block barrier anywhere in this kernel.

    const int p0  = half ? SPLIT : 0;
    const int nch = (half ? (NCOLS - SPLIT) : SPLIT) / 8;   // 43 / 44 chunks
    const uint4* tabs = (const uint4*)g_tab.d;

    float* rl = out + (size_t)row * NCOLS + p0;
    float* ru = rl + (size_t)batch * NCOLS;

    float2 Lc = make_float2(0.0f, 0.0f);  // set by a pair before any triple
                                          // in both halves (p0=344 is a pair)

    for (int k = 0; k < nch; ++k) {
        const uint4 ta = tabs[(p0 >> 2) + 2 * k];
        const uint4 tb = tabs[(p0 >> 2) + 2 * k + 1];
        const uint32_t ds[8] = {ta.x, ta.y, ta.z, ta.w, tb.x, tb.y, tb.z, tb.w};
        float cl[8], cu[8];
#pragma unroll
        for (int s = 0; s < 8; ++s) {
            const uint32_t d = ds[s];            // wave-uniform descriptor
            float2 Vx = vrow[d & 15u];           // stride-17 ds_read_b64,
            float2 Vy = vrow[(d >> 4) & 15u];    // <=4-way aliasing by design
            float2 T1 = selpair(Vy, Vx);
            float2 o;
            if (d & 256u) {                      // uniform (scalar) branch
                o = selpair(Lc, T1);             // triple: L = cached pair
            } else {
                Lc = T1;                         // single/pair: refresh cache
                o  = T1;
            }
            cl[s] = o.x; cu[s] = o.y;            // static index (unrolled)
        }
        v4f a0 = {cl[0], cl[1], cl[2], cl[3]};
        v4f a1 = {cl[4], cl[5], cl[6], cl[7]};
        v4f b0 = {cu[0], cu[1], cu[2], cu[3]};
        v4f b1 = {cu[4], cu[5], cu[6], cu[7]};
        // Row stride 2784 B and chunk base (p0+8k)*4 are both 16B-aligned.
        *(v4f*)(rl + 8 * k)     = a0;
        *(v4f*)(rl + 8 * k + 4) = a1;
        *(v4f*)(ru + 8 * k)     = b0;
        *(v4f*)(ru + 8 * k + 4) = b1;
    }
}

extern "C" void kernel_launch(void* const* d_in, const int* in_sizes, int n_in,
                              void* d_out, int out_size, void* d_ws, size_t ws_size,
                              hipStream_t stream) {
    const float* xl = (const float*)d_in[0];
    const float* xu = (const float*)d_in[1];
    float* out = (float*)d_out;
    const int batch = in_sizes[0] / 16;          // 65536
    const int grid  = batch / (2 * RG);          // 512 blocks: 2 row-groups each
    minint_kernel<<<grid, BLOCK, 0, stream>>>(xl, xu, out, batch);
}

// Round 5
// 374.512 us; speedup vs baseline: 1.6780x; 1.6780x over previous
//
#include <hip/hip_runtime.h>
#include <cstdint>

// ROOFLINE NOTE (R5 analysis): this kernel runs in ~50-58 us, at the HBM
// write floor (365 MB / 6.3 TB/s = 58 us). dur_us ~375 is dominated by the
// harness's 1.46 GB poison fill (~235 us, top-5 in every rocprof capture)
// plus ~90 us fixed launch/serialization overhead. Evidence: R4's lane=row
// variant measured kernel=303 us with dur=628 us; ddur (253) == dkernel
// (303-50), pinning the fixed cost at ~325 us and this kernel at ~50 us.

#define NCOLS  696     // 16 + 120 + 560 subsets of size <= 3, bitmask order
#define NGROUP 174     // NCOLS / 4
#define NREC   136     // 16 singles + 120 pairs
#define RPB    4       // rows per block (one wave per row)
#define BLOCK  256

typedef float v4f __attribute__((ext_vector_type(4)));  // clang vector: ok for nontemporal builtin

// Record id: single a -> a ; pair (a<b) -> 16 + b*(b-1)/2 + a.
constexpr int pr(int a, int b) { return 16 + b * (b - 1) / 2 + a; }

// Per-record source operands (lo | hi<<8): rec[r] = selpair(v[hi], v[lo]).
//  single a: (a,a) -> selpair(I_a, I_a) = I_a (tie, beta tie, choose left).
//  pair (a<b): selpair(L=I_b, R=I_a) = reference pairres(a,b).
struct alignas(8) RecSrc { uint16_t d[NREC]; };
constexpr RecSrc make_recs() {
    RecSrc t{};
    for (int a = 0; a < 16; ++a) t.d[a] = (uint16_t)(a | (a << 8));
    int p = 16;
    for (int b = 1; b < 16; ++b)
        for (int a = 0; a < b; ++a)
            t.d[p++] = (uint16_t)(a | (b << 8));
    return t;
}

// Per-column descriptor (Lrec | Rrec<<8): out = selpair(rec[Lrec], rec[Rrec]).
//  single {h}:   L = R = h            (selpair(X,X) == X)
//  pair {j,h}:   L = R = pr(j,h)
//  triple {i,j,h}: L = pr(j,h) (= combo[1:]), R = pr(i,j) (= combo[:-1])
// Emission order generates subsets sorted by bitmask value.
struct alignas(8) ColTbl { uint16_t d[NCOLS]; };
constexpr ColTbl make_cols() {
    ColTbl t{};
    int p = 0;
    for (int h = 0; h < 16; ++h) {
        t.d[p++] = (uint16_t)(h | (h << 8));
        for (int j = 0; j < h; ++j) {
            int pjh = pr(j, h);
            t.d[p++] = (uint16_t)(pjh | (pjh << 8));
            for (int i = 0; i < j; ++i)
                t.d[p++] = (uint16_t)(pr(j, h) | (pr(i, j) << 8));
        }
    }
    return t;
}

__constant__ RecSrc g_recs = make_recs();
__constant__ ColTbl g_cols = make_cols();

// Tie-exact select. cur comparison uses the sum proxy: RN(0.5l+0.5u) =
// 0.5*RN(l+u) exactly (power-of-two scaling), so ==/> are preserved
// bit-for-bit vs the NumPy fp32 reference. Beta path kept in RN form.
__device__ __forceinline__ float2 selpair(float2 L, float2 R) {
    float curL = __fadd_rn(L.x, L.y);
    float curR = __fadd_rn(R.x, R.y);
    float bL = __fadd_rn(__fmul_rn(0.2f, L.x), __fmul_rn(0.8f, L.y));
    float bR = __fadd_rn(__fmul_rn(0.2f, R.x), __fmul_rn(0.8f, R.y));
    bool choose_right = (curL == curR) ? (bL > bR) : (curL > curR);
    return choose_right ? R : L;
}

__device__ __forceinline__ float2 col_compute(const float2* __restrict__ rec,
                                              uint32_t d) {
    float2 L = rec[d & 255u];
    float2 R = rec[(d >> 8) & 255u];
    return selpair(L, R);
}

__global__ __launch_bounds__(BLOCK) void minint_kernel(
    const float* __restrict__ xl, const float* __restrict__ xu,
    float* __restrict__ out, int batch)
{
    __shared__ float2 vals[RPB][16];
    __shared__ float2 recs[RPB][NREC];
    const int t = threadIdx.x;
    const int base = blockIdx.x * RPB;

    // Stage RPB rows of (xl,xu) into LDS as interleaved float2 intervals.
    if (t < RPB * 16) {
        float a = xl[base * 16 + t];
        float b = xu[base * 16 + t];
        vals[t >> 4][t & 15] = make_float2(a, b);
    }
    __syncthreads();

    const int w    = t >> 6;   // wave id == local row
    const int lane = t & 63;
    const float2* v = vals[w];

    // Precompute the 136 single/pair records for this wave's row.
    for (int r = lane; r < NREC; r += 64) {
        uint32_t s = g_recs.d[r];
        float2 lo = v[s & 15u];
        float2 hi = v[(s >> 8) & 15u];
        recs[w][r] = selpair(hi, lo);
    }
    __syncthreads();

    const int row = base + w;
    const float2* rec = recs[w];
    float* outl = out + (size_t)row * NCOLS;
    float* outu = out + (size_t)batch * NCOLS + (size_t)row * NCOLS;
    const ushort4* cols = (const ushort4*)g_cols.d;

    // 174 groups of 4 columns; lane g handles columns [4g, 4g+4).
    // Row byte stride = 696*4 = 174*16 -> float4 stores stay 16B-aligned.
    for (int g = lane; g < NGROUP; g += 64) {
        ushort4 d4 = cols[g];
        float2 c0 = col_compute(rec, d4.x);
        float2 c1 = col_compute(rec, d4.y);
        float2 c2 = col_compute(rec, d4.z);
        float2 c3 = col_compute(rec, d4.w);
        v4f rl = { c0.x, c1.x, c2.x, c3.x };
        v4f ru = { c0.y, c1.y, c2.y, c3.y };
        __builtin_nontemporal_store(rl, (v4f*)(outl + 4 * g));
        __builtin_nontemporal_store(ru, (v4f*)(outu + 4 * g));
    }
}

extern "C" void kernel_launch(void* const* d_in, const int* in_sizes, int n_in,
                              void* d_out, int out_size, void* d_ws, size_t ws_size,
                              hipStream_t stream) {
    const float* xl = (const float*)d_in[0];
    const float* xu = (const float*)d_in[1];
    float* out = (float*)d_out;
    const int batch = in_sizes[0] / 16;          // 65536
    const int grid  = batch / RPB;               // 16384 blocks x 4 waves
    minint_kernel<<<grid, BLOCK, 0, stream>>>(xl, xu, out, batch);
}